// Round 1
// 357.666 us; speedup vs baseline: 1.0387x; 1.0387x over previous
//
#include <hip/hip_runtime.h>
#include <hip/hip_bf16.h>
#include <cstdint>
#include <cstddef>

typedef __bf16 bf16;
typedef __bf16 bf16x8 __attribute__((ext_vector_type(8)));
typedef __bf16 bf16x4 __attribute__((ext_vector_type(4)));
typedef float f32x4 __attribute__((ext_vector_type(4)));

static constexpr int BATCH = 2;
static constexpr int SEQ = 2048;
static constexpr int DMODEL = 2048;
static constexpr int NH = 16;
static constexpr int HD = 128;
static constexpr int MROWS = BATCH * SEQ; // 4096

#define GLOBAL_AS(p) ((const __attribute__((address_space(1))) void*)(p))
#define LDS_AS(p)    ((__attribute__((address_space(3))) void*)(p))

// ---------------- fused fp32 -> bf16 convert (x, Wq, Wk, Wv, Wo in one launch) ----
// float4-group counts: x = 2,097,152 ; each W = 1,048,576 ; total 6,291,456.
// dst regions are contiguous: xb | Wq | Wk | Wv | Wo.
__global__ void cvt5_kernel(const float* __restrict__ x,
                            const float* __restrict__ wq, const float* __restrict__ wk,
                            const float* __restrict__ wv, const float* __restrict__ wo,
                            bf16* __restrict__ dst) {
  const int i = blockIdx.x * blockDim.x + threadIdx.x;   // global float4 index
  const float* src;
  int local;
  if (i < 2097152) { src = x; local = i; }
  else {
    const int r = i - 2097152;
    const int w = r >> 20;            // 0..3 (block-uniform: 4096 blocks per weight)
    local = r & 1048575;
    src = (w == 0) ? wq : (w == 1) ? wk : (w == 2) ? wv : wo;
  }
  float4 f = reinterpret_cast<const float4*>(src)[local];
  bf16x4 o;
  o.x = (bf16)f.x; o.y = (bf16)f.y; o.z = (bf16)f.z; o.w = (bf16)f.w;
  reinterpret_cast<bf16x4*>(dst)[i] = o;
}

// ---------------- GEMM: C = A(MxK,row) * W(NxK,row)^T ----------------
// m97 structure + rotation swizzle: row r's 16B-chunk c stored at chunk (c+r)&7.
// glds covers 8 rows x 8 chunks per 1KB instr, rbase%8==0 -> lane permutation
// is i-invariant. Fragment read chunk = (ks*4+quad+l16)&7 -> 2-way banks (free).
enum { MODE_QKV = 0, MODE_OUT = 1 };

template <int MODE>
__global__ __launch_bounds__(256, 4) void gemm_bt(
    const bf16* __restrict__ A, const bf16* __restrict__ W,
    bf16* __restrict__ Oq, bf16* __restrict__ Ok, bf16* __restrict__ Ov,
    float* __restrict__ Oout) {
  constexpr int Kd = DMODEL;
  __shared__ __align__(16) bf16 As[128][64];
  __shared__ __align__(16) bf16 Bs[128][64];
  const int n0 = blockIdx.x * 128;
  const int m0 = blockIdx.y * 128;
  const int tid = threadIdx.x;
  const int wave = tid >> 6;
  const int lane = tid & 63;
  const int quad = lane >> 4;
  const int l16 = lane & 15;
  const int wm = (wave >> 1) * 64;
  const int wn = (wave & 1) * 64;
  const int srow = lane >> 3;                       // 0..7 within the 8-row chunk
  const int schunk = ((lane & 7) - srow) & 7;       // logical 16B chunk (swizzle src)

  f32x4 acc[4][4] = {};
  for (int kt = 0; kt < Kd; kt += 64) {
#pragma unroll
    for (int i = 0; i < 4; i++) {
      const int r = wave * 32 + i * 8;              // r % 8 == 0
      __builtin_amdgcn_global_load_lds(
          GLOBAL_AS(&A[(size_t)(m0 + r + srow) * Kd + kt + schunk * 8]),
          LDS_AS(&As[r][0]), 16, 0, 0);
      __builtin_amdgcn_global_load_lds(
          GLOBAL_AS(&W[(size_t)(n0 + r + srow) * Kd + kt + schunk * 8]),
          LDS_AS(&Bs[r][0]), 16, 0, 0);
    }
    __syncthreads();
#pragma unroll
    for (int ks = 0; ks < 2; ks++) {
      const int col = (((ks * 4 + quad + l16) & 7)) * 8;   // swizzled read chunk
      bf16x8 af[4], bfr[4];
#pragma unroll
      for (int t = 0; t < 4; t++)
        af[t] = *reinterpret_cast<const bf16x8*>(&As[wm + t * 16 + l16][col]);
#pragma unroll
      for (int t = 0; t < 4; t++)
        bfr[t] = *reinterpret_cast<const bf16x8*>(&Bs[wn + t * 16 + l16][col]);
#pragma unroll
      for (int tm = 0; tm < 4; tm++)
#pragma unroll
        for (int tn = 0; tn < 4; tn++)
          acc[tm][tn] = __builtin_amdgcn_mfma_f32_16x16x32_bf16(af[tm], bfr[tn], acc[tm][tn], 0, 0, 0);
    }
    __syncthreads();
  }
#pragma unroll
  for (int tm = 0; tm < 4; tm++) {
#pragma unroll
    for (int tn = 0; tn < 4; tn++) {
      const int row0 = m0 + wm + tm * 16 + quad * 4;
      if constexpr (MODE == MODE_OUT) {
        const int col = n0 + wn + tn * 16 + l16;
#pragma unroll
        for (int j = 0; j < 4; j++)
          Oout[(size_t)(row0 + j) * DMODEL + col] = acc[tm][tn][j];
      } else {
        const int mat = n0 >> 11;              // 0=Q 1=K 2=V
        const int col = (n0 & 2047) + wn + tn * 16 + l16;
        const int h = col >> 7, dd = col & 127;
        if (mat == 2) {
          const int b = row0 >> 11, s = row0 & 2047;
          bf16x4 pk;
#pragma unroll
          for (int j = 0; j < 4; j++) pk[j] = (bf16)acc[tm][tn][j];
          *reinterpret_cast<bf16x4*>(&Ov[((size_t)(b * NH + h) * HD + dd) * SEQ + s]) = pk;
        } else {
          bf16* O = mat ? Ok : Oq;
          const float scale = mat ? 1.0f : 0.08838834764831845f;
#pragma unroll
          for (int j = 0; j < 4; j++) {
            const int row = row0 + j;
            const int b = row >> 11, s = row & 2047;
            O[((size_t)(b * NH + h) * SEQ + s) * HD + dd] = (bf16)(acc[tm][tn][j] * scale);
          }
        }
      }
    }
  }
}

// ---------------- flash attention: 2-phase double-buffered K/V staging ----------
// Change vs prev round: Ks/Vts double-buffered (2x16KB each + Ps = 73KB LDS,
// still exactly 2 blocks/CU at 149.5/160KB). Per-iter schedule (T3-minimum):
//   stage(t+1 -> nxt buf)  |  compute(t on cur buf)  |  vmcnt(0) ; s_barrier
// Raw s_barrier (NOT __syncthreads) so the compiler does not drain vmcnt before
// the barrier; the explicit vmcnt(0) after compute lets the next-tile loads fly
// under the whole QK/softmax/PV phase. One barrier per iteration instead of two.
__global__ __launch_bounds__(256, 2) void attn_kernel(
    const bf16* __restrict__ Q, const bf16* __restrict__ K,
    const bf16* __restrict__ Vt, bf16* __restrict__ Y) {
  const int j = blockIdx.x;          // 0..15
  const int bh = blockIdx.y;
  __shared__ __align__(16) char smem[74752];
  auto Ks0 = (bf16(*)[128])(smem);              // [64][128] 16384 B (swizzled)
  auto Ks1 = (bf16(*)[128])(smem + 16384);
  auto Vt0 = (bf16(*)[64])(smem + 32768);       // [128][64] 16384 B (swizzled)
  auto Vt1 = (bf16(*)[64])(smem + 49152);
  auto Ps  = (bf16(*)[16][72])(smem + 65536);   // [4][16][72] 9216 B (padded)
  const int tid = threadIdx.x;
  const int wave = tid >> 6;
  const int lane = tid & 63;
  const int quad = lane >> 4;
  const int l16 = lane & 15;

  const bf16* Kbh = K + (size_t)bh * SEQ * HD;
  const bf16* Vbh = Vt + (size_t)bh * HD * SEQ;
  const int b = bh >> 4, h = bh & 15;

  const int krow = lane >> 4;
  const int vrow = lane >> 3;
  const int vchunk = ((lane & 7) - vrow) & 7;

  // stage one 64-wide K/V tile into the given LDS buffer (8 glds per thread)
  auto stageK = [&](int kt, bf16 (*Kd)[128]) {
#pragma unroll
    for (int i = 0; i < 4; i++) {
      const int rbase = wave * 16 + i * 4;
      const int r = rbase + krow;
      const int c = ((lane & 15) - krow - i * 4) & 15;
      __builtin_amdgcn_global_load_lds(
          GLOBAL_AS(&Kbh[(size_t)(kt + r) * HD + c * 8]), LDS_AS(&Kd[rbase][0]), 16, 0, 0);
    }
  };
  auto stageV = [&](int kt, bf16 (*Vd)[64]) {
#pragma unroll
    for (int i = 0; i < 4; i++) {
      const int rbase = wave * 32 + i * 8;
      const int r = rbase + vrow;
      __builtin_amdgcn_global_load_lds(
          GLOBAL_AS(&Vbh[(size_t)r * SEQ + kt + vchunk * 8]), LDS_AS(&Vd[rbase][0]), 16, 0, 0);
    }
  };

  for (int pass = 0; pass < 2; ++pass) {
    const int qt = pass ? (31 - j) : j;
    const int q0 = qt * 64;
    const int ntiles = qt + 1;

    const bf16* Qw = Q + ((size_t)bh * SEQ + q0 + wave * 16) * HD;
    bf16x8 qf[4];
#pragma unroll
    for (int kk = 0; kk < 4; kk++)
      qf[kk] = *reinterpret_cast<const bf16x8*>(&Qw[(size_t)l16 * HD + kk * 32 + quad * 8]);

    f32x4 oacc[8] = {};
    float m_i = -3.0e38f, l_i = 0.f;

    // prologue: stage tile 0 into buf0, drain, sync
    stageK(0, Ks0);
    stageV(0, Vt0);
    asm volatile("s_waitcnt vmcnt(0)" ::: "memory");
    __builtin_amdgcn_s_barrier();
    __builtin_amdgcn_sched_barrier(0);

    for (int t = 0; t < ntiles; ++t) {
      bf16 (*Ksc)[128] = (t & 1) ? Ks1 : Ks0;
      bf16 (*Vtc)[64]  = (t & 1) ? Vt1 : Vt0;
      // issue next tile's stage into the other buffer BEFORE compute
      if (t + 1 < ntiles) {
        bf16 (*Ksn)[128] = (t & 1) ? Ks0 : Ks1;
        bf16 (*Vtn)[64]  = (t & 1) ? Vt0 : Vt1;
        stageK((t + 1) * 64, Ksn);
        stageV((t + 1) * 64, Vtn);
      }

      f32x4 sacc[4] = {};
#pragma unroll
      for (int kk = 0; kk < 4; kk++) {
        const int kcol = (((kk * 4 + quad + l16) & 15)) * 8;
        bf16x8 ka[4];
#pragma unroll
        for (int mt = 0; mt < 4; mt++)
          ka[mt] = *reinterpret_cast<const bf16x8*>(&Ksc[mt * 16 + l16][kcol]);
#pragma unroll
        for (int mt = 0; mt < 4; mt++)
          sacc[mt] = __builtin_amdgcn_mfma_f32_16x16x32_bf16(ka[mt], qf[kk], sacc[mt], 0, 0, 0);
      }

      const int qg_loc = wave * 16 + l16;
      float mx = -3.0e38f;
      if (t == ntiles - 1) {
#pragma unroll
        for (int mt = 0; mt < 4; mt++)
#pragma unroll
          for (int jj = 0; jj < 4; jj++) {
            const int kg = mt * 16 + quad * 4 + jj;
            float v = (kg <= qg_loc) ? sacc[mt][jj] : -3.0e38f;
            sacc[mt][jj] = v;
            mx = fmaxf(mx, v);
          }
      } else {
#pragma unroll
        for (int mt = 0; mt < 4; mt++)
#pragma unroll
          for (int jj = 0; jj < 4; jj++) mx = fmaxf(mx, sacc[mt][jj]);
      }
      mx = fmaxf(mx, __shfl_xor(mx, 16));
      mx = fmaxf(mx, __shfl_xor(mx, 32));
      const float mnew = fmaxf(m_i, mx);
      const float alpha = __expf(m_i - mnew);
      m_i = mnew;
      float rs = 0.f;
#pragma unroll
      for (int mt = 0; mt < 4; mt++)
#pragma unroll
        for (int jj = 0; jj < 4; jj++) {
          float p = __expf(sacc[mt][jj] - mnew);
          sacc[mt][jj] = p;
          rs += p;
        }
      rs += __shfl_xor(rs, 16);
      rs += __shfl_xor(rs, 32);
      l_i = l_i * alpha + rs;
#pragma unroll
      for (int mt8 = 0; mt8 < 8; mt8++)
#pragma unroll
        for (int jj = 0; jj < 4; jj++) oacc[mt8][jj] *= alpha;

#pragma unroll
      for (int mt = 0; mt < 4; mt++) {
        bf16x4 pk;
#pragma unroll
        for (int jj = 0; jj < 4; jj++) pk[jj] = (bf16)sacc[mt][jj];
        *reinterpret_cast<bf16x4*>(&Ps[wave][l16][mt * 16 + quad * 4]) = pk;
      }

#pragma unroll
      for (int kk2 = 0; kk2 < 2; kk2++) {
        const int vcol = ((kk2 * 4 + quad + l16) & 7) * 8;
        bf16x8 pb = *reinterpret_cast<const bf16x8*>(&Ps[wave][l16][kk2 * 32 + quad * 8]);
#pragma unroll
        for (int mt8 = 0; mt8 < 8; mt8++) {
          bf16x8 av = *reinterpret_cast<const bf16x8*>(&Vtc[mt8 * 16 + l16][vcol]);
          oacc[mt8] = __builtin_amdgcn_mfma_f32_16x16x32_bf16(av, pb, oacc[mt8], 0, 0, 0);
        }
      }

      // drain this iter's prefetch, then sync: next iter may read nxt buf and
      // overwrite cur buf's stage target.
      asm volatile("s_waitcnt vmcnt(0)" ::: "memory");
      __builtin_amdgcn_s_barrier();
      __builtin_amdgcn_sched_barrier(0);
    }

    const float inv = 1.0f / l_i;
    const int qg = q0 + wave * 16 + l16;
#pragma unroll
    for (int mt8 = 0; mt8 < 8; mt8++) {
      bf16x4 pk;
#pragma unroll
      for (int jj = 0; jj < 4; jj++) pk[jj] = (bf16)(oacc[mt8][jj] * inv);
      *reinterpret_cast<bf16x4*>(
          &Y[(size_t)(b * SEQ + qg) * DMODEL + h * HD + mt8 * 16 + quad * 4]) = pk;
    }
  }
}

// ---------------- launch ----------------
extern "C" void kernel_launch(void* const* d_in, const int* in_sizes, int n_in,
                              void* d_out, int out_size, void* d_ws, size_t ws_size,
                              hipStream_t stream) {
  const float* x  = (const float*)d_in[0];
  const float* Wq = (const float*)d_in[2];
  const float* Wk = (const float*)d_in[3];
  const float* Wv = (const float*)d_in[4];
  const float* Wo = (const float*)d_in[5];
  float* out = (float*)d_out;

  char* ws = (char*)d_ws;
  bf16* xb  = (bf16*)(ws + 0);
  bf16* Wqb = (bf16*)(ws + 16777216);    // Wq,Wk,Wv contiguous -> one [6144][2048]
  bf16* Wob = (bf16*)(ws + 41943040);
  bf16* Qb  = (bf16*)(ws + 50331648);    // [B,H,S,d]
  bf16* Kb  = (bf16*)(ws + 67108864);    // [B,H,S,d]
  bf16* Vtb = (bf16*)(ws + 83886080);    // [B,H,d,S]
  bf16* Yb  = xb;                        // [B,S,D] (x dead after projections)
  if (ws_size < 100663296) return;

  // one fused convert: 6,291,456 float4 groups -> 24576 blocks
  cvt5_kernel<<<24576, 256, 0, stream>>>(x, Wq, Wk, Wv, Wo, xb);

  gemm_bt<MODE_QKV><<<dim3(48, MROWS / 128), 256, 0, stream>>>(
      xb, Wqb, Qb, Kb, Vtb, nullptr);

  attn_kernel<<<dim3(16, BATCH * NH), 256, 0, stream>>>(Qb, Kb, Vtb, Yb);

  gemm_bt<MODE_OUT><<<dim3(16, MROWS / 128), 256, 0, stream>>>(
      Yb, Wob, nullptr, nullptr, nullptr, out);
}